// Round 1
// baseline (1915.887 us; speedup 1.0000x reference)
//
#include <hip/hip_runtime.h>

// GAT 3-layer (N=50000, E=800000 (+N self loops), H=2, C=64, all feature widths 128)
// fp32 correctness-first implementation.
//
// Pipeline per layer:
//   gemm128      : H = in @ W            [N,128]
//   att_logits   : al_s/al_d = <h, a_*>  [N,2]
//   edge_logit_max: e=leaky(al_s[s]+al_d[d]); store e; atomicMax seg-max (ordered-uint)
//   edge_exp     : ex=exp(e-m[d]); store; atomicAdd seg-sum den
//   aggregate    : A[d] += h[s]*ex/(den[d]+1e-16)   (wave = 64 consecutive channels)
//   bn_stats/bn_apply (+relu) for layers 0,1 — bias b0/b1 cancels under train-BN, skipped
//   head_mean (+b2) for layer 2 -> d_out [N,64]

#define N_NODES 50000
#define N_EDGES 800000
#define ET (N_EDGES + N_NODES)   // 850000 incl self loops
#define FDIM 128
#define SLOPE 0.2f
#define BN_EPS 1e-5f

__device__ __forceinline__ unsigned f2ord(float f) {
  unsigned u = __float_as_uint(f);
  return (u & 0x80000000u) ? ~u : (u | 0x80000000u);
}
__device__ __forceinline__ float ord2f(unsigned u) {
  unsigned b = (u & 0x80000000u) ? (u & 0x7fffffffu) : ~u;
  return __uint_as_float(b);
}

// Y[N,128] = X[N,128] @ W[128,128]; block = 256 thr = 128 cols x 2 row-groups, 4 rows each.
__global__ __launch_bounds__(256) void gemm128(const float* __restrict__ X,
                                               const float* __restrict__ W,
                                               float* __restrict__ Y) {
  int col = threadIdx.x & 127;
  int rg  = threadIdx.x >> 7;
  int row0 = blockIdx.x * 8 + rg * 4;
  const float* x0 = X + (size_t)row0 * FDIM;
  float a0 = 0.f, a1 = 0.f, a2 = 0.f, a3 = 0.f;
#pragma unroll 4
  for (int k = 0; k < FDIM; ++k) {
    float w = W[(k << 7) + col];
    a0 = fmaf(x0[k],            w, a0);
    a1 = fmaf(x0[FDIM + k],     w, a1);
    a2 = fmaf(x0[2 * FDIM + k], w, a2);
    a3 = fmaf(x0[3 * FDIM + k], w, a3);
  }
  float* y = Y + (size_t)row0 * FDIM + col;
  y[0] = a0; y[FDIM] = a1; y[2 * FDIM] = a2; y[3 * FDIM] = a3;
}

// al_s[n,h] = sum_c H[n,h,c]*a_src[h,c]; al_d likewise. one thread per (n,h).
__global__ __launch_bounds__(256) void att_logits(const float* __restrict__ Hf,
                                                  const float* __restrict__ a_src,
                                                  const float* __restrict__ a_dst,
                                                  float* __restrict__ al_s,
                                                  float* __restrict__ al_d) {
  int i = blockIdx.x * 256 + threadIdx.x;
  if (i >= N_NODES * 2) return;
  int hd = i & 1;
  const float* hp = Hf + (size_t)(i >> 1) * FDIM + hd * 64;
  const float* as = a_src + hd * 64;
  const float* ad = a_dst + hd * 64;
  float s = 0.f, d = 0.f;
#pragma unroll 8
  for (int c = 0; c < 64; ++c) {
    float v = hp[c];
    s = fmaf(v, as[c], s);
    d = fmaf(v, ad[c], d);
  }
  al_s[i] = s;
  al_d[i] = d;
}

// one thread per (edge, head); edges >= N_EDGES are self loops (s=d=e-N_EDGES)
__global__ __launch_bounds__(256) void edge_logit_max(const int* __restrict__ src,
                                                      const int* __restrict__ dst,
                                                      const float* __restrict__ al_s,
                                                      const float* __restrict__ al_d,
                                                      float* __restrict__ ev,
                                                      unsigned* __restrict__ mmax) {
  int i = blockIdx.x * 256 + threadIdx.x;
  if (i >= ET * 2) return;
  int e = i >> 1, hd = i & 1;
  int s, d;
  if (e < N_EDGES) { s = src[e]; d = dst[e]; } else { s = d = e - N_EDGES; }
  float v = al_s[s * 2 + hd] + al_d[d * 2 + hd];
  v = v > 0.f ? v : SLOPE * v;
  ev[i] = v;
  atomicMax(&mmax[d * 2 + hd], f2ord(v));
}

__global__ __launch_bounds__(256) void edge_exp(const int* __restrict__ dst,
                                                const unsigned* __restrict__ mmax,
                                                float* __restrict__ ev,
                                                float* __restrict__ den) {
  int i = blockIdx.x * 256 + threadIdx.x;
  if (i >= ET * 2) return;
  int e = i >> 1, hd = i & 1;
  int d = (e < N_EDGES) ? dst[e] : e - N_EDGES;
  float m = ord2f(mmax[d * 2 + hd]);
  float x = __expf(ev[i] - m);
  ev[i] = x;
  atomicAdd(&den[d * 2 + hd], x);
}

// one thread per (edge, channel); a wave covers 64 consecutive channels of one edge
__global__ __launch_bounds__(256) void aggregate(const int* __restrict__ src,
                                                 const int* __restrict__ dst,
                                                 const float* __restrict__ Hf,
                                                 const float* __restrict__ ev,
                                                 const float* __restrict__ den,
                                                 float* __restrict__ A) {
  int idx = blockIdx.x * 256 + threadIdx.x;   // ET*128 = 108.8M < 2^31
  if (idx >= ET * FDIM) return;
  int e = idx >> 7, c = idx & 127, hd = c >> 6;
  int s, d;
  if (e < N_EDGES) { s = src[e]; d = dst[e]; } else { s = d = e - N_EDGES; }
  float alpha = ev[e * 2 + hd] / (den[d * 2 + hd] + 1e-16f);
  atomicAdd(&A[(size_t)d * FDIM + c], Hf[(size_t)s * FDIM + c] * alpha);
}

// per-channel sum / sumsq over N rows. thread t owns channel t&127 (stride multiple of 128).
__global__ __launch_bounds__(256) void bn_stats(const float* __restrict__ A,
                                                float* __restrict__ acc) {
  __shared__ float sh[512];
  int tid = threadIdx.x;
  float s = 0.f, q = 0.f;
  for (int i = blockIdx.x * 256 + tid; i < N_NODES * FDIM; i += gridDim.x * 256) {
    float v = A[i];
    s += v;
    q = fmaf(v, v, q);
  }
  sh[tid] = s;
  sh[256 + tid] = q;
  __syncthreads();
  if (tid < 128) {
    atomicAdd(&acc[tid],       sh[tid] + sh[tid + 128]);
    atomicAdd(&acc[128 + tid], sh[256 + tid] + sh[256 + tid + 128]);
  }
}

__global__ __launch_bounds__(256) void bn_apply(float* __restrict__ A,
                                                const float* __restrict__ acc,
                                                const float* __restrict__ g,
                                                const float* __restrict__ be) {
  int i = blockIdx.x * 256 + threadIdx.x;
  if (i >= N_NODES * FDIM) return;
  int c = i & 127;
  float mu  = acc[c] * (1.f / N_NODES);
  float var = acc[128 + c] * (1.f / N_NODES) - mu * mu;
  float v = (A[i] - mu) * rsqrtf(var + BN_EPS) * g[c] + be[c];
  A[i] = v > 0.f ? v : 0.f;
}

__global__ __launch_bounds__(256) void head_mean(const float* __restrict__ A,
                                                 const float* __restrict__ b2,
                                                 float* __restrict__ out) {
  int i = blockIdx.x * 256 + threadIdx.x;
  if (i >= N_NODES * 64) return;
  int n = i >> 6, c = i & 63;
  out[i] = 0.5f * (A[(size_t)n * FDIM + c] + A[(size_t)n * FDIM + 64 + c]) + b2[c];
}

extern "C" void kernel_launch(void* const* d_in, const int* in_sizes, int n_in,
                              void* d_out, int out_size, void* d_ws, size_t ws_size,
                              hipStream_t stream) {
  const float* x  = (const float*)d_in[0];
  const int*   ei = (const int*)d_in[1];          // [2, E] int32
  const int* src = ei;
  const int* dst = ei + N_EDGES;

  const float* W[3]    = {(const float*)d_in[2],  (const float*)d_in[8],  (const float*)d_in[14]};
  const float* asrc[3] = {(const float*)d_in[3],  (const float*)d_in[9],  (const float*)d_in[15]};
  const float* adst[3] = {(const float*)d_in[4],  (const float*)d_in[10], (const float*)d_in[16]};
  const float* g[2]    = {(const float*)d_in[6],  (const float*)d_in[12]};
  const float* be[2]   = {(const float*)d_in[7],  (const float*)d_in[13]};
  const float* b2      = (const float*)d_in[17];

  // workspace layout (floats):
  // [A: N*128][mmax: N*2 (u32)][den: N*2][bna: 256][al_s: N*2][al_d: N*2][H: N*128][ev: ET*2]
  float* A      = (float*)d_ws;
  unsigned* mmax = (unsigned*)(A + (size_t)N_NODES * FDIM);
  float* den    = (float*)(mmax + (size_t)N_NODES * 2);
  float* bna    = den + (size_t)N_NODES * 2;
  float* als    = bna + 256;
  float* ald    = als + (size_t)N_NODES * 2;
  float* Hbuf   = ald + (size_t)N_NODES * 2;
  float* ev     = Hbuf + (size_t)N_NODES * FDIM;

  // zero A + mmax + den + bna in one shot (contiguous at front of ws)
  size_t zero_bytes = ((size_t)N_NODES * FDIM + (size_t)N_NODES * 4 + 256) * sizeof(float);

  for (int L = 0; L < 3; ++L) {
    const float* fin = (L == 0) ? x : A;
    gemm128<<<N_NODES / 8, 256, 0, stream>>>(fin, W[L], Hbuf);
    hipMemsetAsync(d_ws, 0, zero_bytes, stream);   // after gemm consumed A
    att_logits<<<(N_NODES * 2 + 255) / 256, 256, 0, stream>>>(Hbuf, asrc[L], adst[L], als, ald);
    edge_logit_max<<<(ET * 2 + 255) / 256, 256, 0, stream>>>(src, dst, als, ald, ev, mmax);
    edge_exp<<<(ET * 2 + 255) / 256, 256, 0, stream>>>(dst, mmax, ev, den);
    aggregate<<<(ET * FDIM + 255) / 256, 256, 0, stream>>>(src, dst, Hbuf, ev, den, A);
    if (L < 2) {
      bn_stats<<<1024, 256, 0, stream>>>(A, bna);
      bn_apply<<<(N_NODES * FDIM + 255) / 256, 256, 0, stream>>>(A, bna, g[L], be[L]);
    } else {
      head_mean<<<(N_NODES * 64 + 255) / 256, 256, 0, stream>>>(A, b2, (float*)d_out);
    }
  }
}

// Round 2
// 1304.412 us; speedup vs baseline: 1.4688x; 1.4688x over previous
//
#include <hip/hip_runtime.h>

// GAT 3-layer (N=50000, E=800000 (+N self loops), H=2, C=64, widths 128)
// Round 2: dst-sorted CSR (built once per call) + fused online-softmax
// aggregation (one wave per node-head). No atomics on the feature matrix.

#define N_NODES 50000
#define N_EDGES 800000
#define ET (N_EDGES + N_NODES)   // 850000 incl self loops
#define FDIM 128
#define SLOPE 0.2f
#define BN_EPS 1e-5f

// ---------------- CSR build ----------------

__global__ __launch_bounds__(256) void hist_kernel(const int* __restrict__ dst,
                                                   int* __restrict__ counts) {
  int i = blockIdx.x * 256 + threadIdx.x;
  if (i >= ET) return;
  int d = (i < N_EDGES) ? dst[i] : i - N_EDGES;
  atomicAdd(&counts[d], 1);
}

// single-block exclusive scan over counts[0..N-1] -> rowptr[0..N], fill copy
__global__ __launch_bounds__(1024) void scan_kernel(const int* __restrict__ counts,
                                                    int* __restrict__ rowptr,
                                                    int* __restrict__ fill) {
  __shared__ int sums[1024];
  int t = threadIdx.x;
  const int CH = (N_NODES + 1023) / 1024;   // 49
  int base = t * CH;
  int s = 0;
  for (int i = 0; i < CH; ++i) {
    int idx = base + i;
    if (idx < N_NODES) s += counts[idx];
  }
  sums[t] = s;
  __syncthreads();
  for (int off = 1; off < 1024; off <<= 1) {
    int v = (t >= off) ? sums[t - off] : 0;
    __syncthreads();
    sums[t] += v;
    __syncthreads();
  }
  int run = (t == 0) ? 0 : sums[t - 1];
  for (int i = 0; i < CH; ++i) {
    int idx = base + i;
    if (idx < N_NODES) {
      rowptr[idx] = run;
      fill[idx] = run;
      run += counts[idx];
    }
  }
  if (t == 1023) rowptr[N_NODES] = run;   // == ET
}

__global__ __launch_bounds__(256) void scatter_kernel(const int* __restrict__ src,
                                                      const int* __restrict__ dst,
                                                      int* __restrict__ fill,
                                                      int* __restrict__ csr_src) {
  int i = blockIdx.x * 256 + threadIdx.x;
  if (i >= ET) return;
  int s, d;
  if (i < N_EDGES) { s = src[i]; d = dst[i]; } else { s = d = i - N_EDGES; }
  int pos = atomicAdd(&fill[d], 1);
  csr_src[pos] = s;
}

// ---------------- per-layer kernels ----------------

// Y[N,128] = X[N,128] @ W[128,128]; block = 256 thr = 128 cols x 2 row-groups, 4 rows each.
__global__ __launch_bounds__(256) void gemm128(const float* __restrict__ X,
                                               const float* __restrict__ W,
                                               float* __restrict__ Y) {
  int col = threadIdx.x & 127;
  int rg  = threadIdx.x >> 7;
  int row0 = blockIdx.x * 8 + rg * 4;
  const float* x0 = X + (size_t)row0 * FDIM;
  float a0 = 0.f, a1 = 0.f, a2 = 0.f, a3 = 0.f;
#pragma unroll 4
  for (int k = 0; k < FDIM; ++k) {
    float w = W[(k << 7) + col];
    a0 = fmaf(x0[k],            w, a0);
    a1 = fmaf(x0[FDIM + k],     w, a1);
    a2 = fmaf(x0[2 * FDIM + k], w, a2);
    a3 = fmaf(x0[3 * FDIM + k], w, a3);
  }
  float* y = Y + (size_t)row0 * FDIM + col;
  y[0] = a0; y[FDIM] = a1; y[2 * FDIM] = a2; y[3 * FDIM] = a3;
}

// al_s[n,h] = sum_c H[n,h,c]*a_src[h,c]; al_d likewise. one thread per (n,h).
__global__ __launch_bounds__(256) void att_logits(const float* __restrict__ Hf,
                                                  const float* __restrict__ a_src,
                                                  const float* __restrict__ a_dst,
                                                  float* __restrict__ al_s,
                                                  float* __restrict__ al_d) {
  int i = blockIdx.x * 256 + threadIdx.x;
  if (i >= N_NODES * 2) return;
  int hd = i & 1;
  const float* hp = Hf + (size_t)(i >> 1) * FDIM + hd * 64;
  const float* as = a_src + hd * 64;
  const float* ad = a_dst + hd * 64;
  float s = 0.f, d = 0.f;
#pragma unroll 8
  for (int c = 0; c < 64; ++c) {
    float v = hp[c];
    s = fmaf(v, as[c], s);
    d = fmaf(v, ad[c], d);
  }
  al_s[i] = s;
  al_d[i] = d;
}

// fused leaky-softmax-aggregate: one wave per (node, head), lane = channel.
// online softmax over the node's CSR edge range; writes A[n, hd*64+lane] once.
__global__ __launch_bounds__(256) void fused_agg(const int* __restrict__ rowptr,
                                                 const int* __restrict__ csr_src,
                                                 const float* __restrict__ Hf,
                                                 const float* __restrict__ als,
                                                 const float* __restrict__ ald,
                                                 float* __restrict__ A) {
  int wid = (blockIdx.x * 256 + threadIdx.x) >> 6;
  int lane = threadIdx.x & 63;
  if (wid >= N_NODES * 2) return;
  int n = wid >> 1, hd = wid & 1;
  int beg = rowptr[n], end = rowptr[n + 1];
  float ad = ald[n * 2 + hd];
  float m = -__builtin_inff(), l = 0.f, o = 0.f;
  for (int j = beg; j < end; ++j) {
    int s = csr_src[j];
    float v = als[s * 2 + hd] + ad;
    v = v > 0.f ? v : SLOPE * v;
    float h = Hf[(size_t)s * FDIM + hd * 64 + lane];
    float nm = fmaxf(m, v);
    float sc = __expf(m - nm);     // first iter: exp(-inf) = 0
    float ex = __expf(v - nm);
    l = fmaf(l, sc, ex);
    o = fmaf(o, sc, ex * h);
    m = nm;
  }
  A[(size_t)n * FDIM + hd * 64 + lane] = o / (l + 1e-16f);
}

// per-channel sum / sumsq over N rows.
__global__ __launch_bounds__(256) void bn_stats(const float* __restrict__ A,
                                                float* __restrict__ acc) {
  __shared__ float sh[512];
  int tid = threadIdx.x;
  float s = 0.f, q = 0.f;
  for (int i = blockIdx.x * 256 + tid; i < N_NODES * FDIM; i += gridDim.x * 256) {
    float v = A[i];
    s += v;
    q = fmaf(v, v, q);
  }
  sh[tid] = s;
  sh[256 + tid] = q;
  __syncthreads();
  if (tid < 128) {
    atomicAdd(&acc[tid],       sh[tid] + sh[tid + 128]);
    atomicAdd(&acc[128 + tid], sh[256 + tid] + sh[256 + tid + 128]);
  }
}

__global__ __launch_bounds__(256) void bn_apply(float* __restrict__ A,
                                                const float* __restrict__ acc,
                                                const float* __restrict__ g,
                                                const float* __restrict__ be) {
  int i = blockIdx.x * 256 + threadIdx.x;
  if (i >= N_NODES * FDIM) return;
  int c = i & 127;
  float mu  = acc[c] * (1.f / N_NODES);
  float var = acc[128 + c] * (1.f / N_NODES) - mu * mu;
  float v = (A[i] - mu) * rsqrtf(var + BN_EPS) * g[c] + be[c];
  A[i] = v > 0.f ? v : 0.f;
}

__global__ __launch_bounds__(256) void head_mean(const float* __restrict__ A,
                                                 const float* __restrict__ b2,
                                                 float* __restrict__ out) {
  int i = blockIdx.x * 256 + threadIdx.x;
  if (i >= N_NODES * 64) return;
  int n = i >> 6, c = i & 63;
  out[i] = 0.5f * (A[(size_t)n * FDIM + c] + A[(size_t)n * FDIM + 64 + c]) + b2[c];
}

extern "C" void kernel_launch(void* const* d_in, const int* in_sizes, int n_in,
                              void* d_out, int out_size, void* d_ws, size_t ws_size,
                              hipStream_t stream) {
  const float* x  = (const float*)d_in[0];
  const int*   ei = (const int*)d_in[1];          // [2, E] int32
  const int* src = ei;
  const int* dst = ei + N_EDGES;

  const float* W[3]    = {(const float*)d_in[2],  (const float*)d_in[8],  (const float*)d_in[14]};
  const float* asrc[3] = {(const float*)d_in[3],  (const float*)d_in[9],  (const float*)d_in[15]};
  const float* adst[3] = {(const float*)d_in[4],  (const float*)d_in[10], (const float*)d_in[16]};
  const float* g[2]    = {(const float*)d_in[6],  (const float*)d_in[12]};
  const float* be[2]   = {(const float*)d_in[7],  (const float*)d_in[13]};
  const float* b2      = (const float*)d_in[17];

  // workspace layout (4-byte units):
  // [counts N][rowptr N+1][fill N][csr_src ET][bna 256][als 2N][ald 2N][H N*128][A N*128]
  int*   counts  = (int*)d_ws;
  int*   rowptr  = counts + N_NODES;
  int*   fill    = rowptr + (N_NODES + 1);
  int*   csr_src = fill + N_NODES;
  float* bna     = (float*)(csr_src + ET);
  float* als     = bna + 256;
  float* ald     = als + (size_t)N_NODES * 2;
  float* Hbuf    = ald + (size_t)N_NODES * 2;
  float* A       = Hbuf + (size_t)N_NODES * FDIM;

  // ---- build CSR (edges identical across layers) ----
  hipMemsetAsync(counts, 0, (size_t)N_NODES * sizeof(int), stream);
  hist_kernel<<<(ET + 255) / 256, 256, 0, stream>>>(dst, counts);
  scan_kernel<<<1, 1024, 0, stream>>>(counts, rowptr, fill);
  scatter_kernel<<<(ET + 255) / 256, 256, 0, stream>>>(src, dst, fill, csr_src);

  for (int L = 0; L < 3; ++L) {
    const float* fin = (L == 0) ? x : A;
    gemm128<<<N_NODES / 8, 256, 0, stream>>>(fin, W[L], Hbuf);
    att_logits<<<(N_NODES * 2 + 255) / 256, 256, 0, stream>>>(Hbuf, asrc[L], adst[L], als, ald);
    fused_agg<<<(N_NODES * 2 * 64 + 255) / 256, 256, 0, stream>>>(rowptr, csr_src, Hbuf, als, ald, A);
    if (L < 2) {
      hipMemsetAsync(bna, 0, 256 * sizeof(float), stream);
      bn_stats<<<1024, 256, 0, stream>>>(A, bna);
      bn_apply<<<(N_NODES * FDIM + 255) / 256, 256, 0, stream>>>(A, bna, g[L], be[L]);
    } else {
      head_mean<<<(N_NODES * 64 + 255) / 256, 256, 0, stream>>>(A, b2, (float*)d_out);
    }
  }
}

// Round 3
// 1081.931 us; speedup vs baseline: 1.7708x; 1.2056x over previous
//
#include <hip/hip_runtime.h>

// GAT 3-layer (N=50000, E=800000 (+N self loops), H=2, C=64, widths 128)
// Round 3: two-head fused_agg (wave per node, float2 lanes, 1-deep prefetch),
// att_logits folded into gemm epilogue (shfl butterfly), float4 gemm loads.

#define N_NODES 50000
#define N_EDGES 800000
#define ET (N_EDGES + N_NODES)   // 850000 incl self loops
#define FDIM 128
#define SLOPE 0.2f
#define BN_EPS 1e-5f

// ---------------- CSR build ----------------

__global__ __launch_bounds__(256) void hist_kernel(const int* __restrict__ dst,
                                                   int* __restrict__ counts) {
  int i = blockIdx.x * 256 + threadIdx.x;
  if (i >= ET) return;
  int d = (i < N_EDGES) ? dst[i] : i - N_EDGES;
  atomicAdd(&counts[d], 1);
}

// single-block exclusive scan over counts[0..N-1] -> rowptr[0..N], fill copy
__global__ __launch_bounds__(1024) void scan_kernel(const int* __restrict__ counts,
                                                    int* __restrict__ rowptr,
                                                    int* __restrict__ fill) {
  __shared__ int sums[1024];
  int t = threadIdx.x;
  const int CH = (N_NODES + 1023) / 1024;   // 49
  int base = t * CH;
  int s = 0;
  for (int i = 0; i < CH; ++i) {
    int idx = base + i;
    if (idx < N_NODES) s += counts[idx];
  }
  sums[t] = s;
  __syncthreads();
  for (int off = 1; off < 1024; off <<= 1) {
    int v = (t >= off) ? sums[t - off] : 0;
    __syncthreads();
    sums[t] += v;
    __syncthreads();
  }
  int run = (t == 0) ? 0 : sums[t - 1];
  for (int i = 0; i < CH; ++i) {
    int idx = base + i;
    if (idx < N_NODES) {
      rowptr[idx] = run;
      fill[idx] = run;
      run += counts[idx];
    }
  }
  if (t == 1023) rowptr[N_NODES] = run;   // == ET
}

__global__ __launch_bounds__(256) void scatter_kernel(const int* __restrict__ src,
                                                      const int* __restrict__ dst,
                                                      int* __restrict__ fill,
                                                      int* __restrict__ csr_src) {
  int i = blockIdx.x * 256 + threadIdx.x;
  if (i >= ET) return;
  int s, d;
  if (i < N_EDGES) { s = src[i]; d = dst[i]; } else { s = d = i - N_EDGES; }
  int pos = atomicAdd(&fill[d], 1);
  csr_src[pos] = s;
}

// ---------------- per-layer kernels ----------------

// Y[N,128] = X[N,128] @ W[128,128], plus attention-logit epilogue:
//   als[n,h] = <y[n, h*64:(h+1)*64], a_src[h]>, ald likewise.
// block = 256 thr = 128 cols x 2 row-groups, 4 rows each; each wave covers
// exactly one head's 64 cols -> 64-lane butterfly gives the head dot.
__global__ __launch_bounds__(256) void gemm128(const float* __restrict__ X,
                                               const float* __restrict__ W,
                                               const float* __restrict__ a_src,
                                               const float* __restrict__ a_dst,
                                               float* __restrict__ Y,
                                               float* __restrict__ als,
                                               float* __restrict__ ald) {
  int col = threadIdx.x & 127;
  int rg  = threadIdx.x >> 7;
  int row0 = blockIdx.x * 8 + rg * 4;
  const float4* x4 = (const float4*)(X + (size_t)row0 * FDIM);
  float a0 = 0.f, a1 = 0.f, a2 = 0.f, a3 = 0.f;
#pragma unroll 4
  for (int k4 = 0; k4 < 32; ++k4) {
    float4 xa = x4[k4];
    float4 xb = x4[32 + k4];
    float4 xc = x4[64 + k4];
    float4 xd = x4[96 + k4];
    const float* wp = W + ((k4 * 4) << 7) + col;
    float w0 = wp[0], w1 = wp[128], w2 = wp[256], w3 = wp[384];
    a0 = fmaf(xa.x, w0, a0); a0 = fmaf(xa.y, w1, a0); a0 = fmaf(xa.z, w2, a0); a0 = fmaf(xa.w, w3, a0);
    a1 = fmaf(xb.x, w0, a1); a1 = fmaf(xb.y, w1, a1); a1 = fmaf(xb.z, w2, a1); a1 = fmaf(xb.w, w3, a1);
    a2 = fmaf(xc.x, w0, a2); a2 = fmaf(xc.y, w1, a2); a2 = fmaf(xc.z, w2, a2); a2 = fmaf(xc.w, w3, a2);
    a3 = fmaf(xd.x, w0, a3); a3 = fmaf(xd.y, w1, a3); a3 = fmaf(xd.z, w2, a3); a3 = fmaf(xd.w, w3, a3);
  }
  float* y = Y + (size_t)row0 * FDIM + col;
  y[0] = a0; y[FDIM] = a1; y[2 * FDIM] = a2; y[3 * FDIM] = a3;

  // epilogue: attention logits. a_src/a_dst flat [2*64]; index == col.
  float as = a_src[col], ac = a_dst[col];
  float s0 = a0 * as, s1 = a1 * as, s2 = a2 * as, s3 = a3 * as;
  float d0 = a0 * ac, d1 = a1 * ac, d2 = a2 * ac, d3 = a3 * ac;
#pragma unroll
  for (int off = 32; off > 0; off >>= 1) {
    s0 += __shfl_xor(s0, off); s1 += __shfl_xor(s1, off);
    s2 += __shfl_xor(s2, off); s3 += __shfl_xor(s3, off);
    d0 += __shfl_xor(d0, off); d1 += __shfl_xor(d1, off);
    d2 += __shfl_xor(d2, off); d3 += __shfl_xor(d3, off);
  }
  int lane = threadIdx.x & 63;
  if (lane == 0) {
    int hd = col >> 6;   // wave-uniform
    als[(row0 + 0) * 2 + hd] = s0; als[(row0 + 1) * 2 + hd] = s1;
    als[(row0 + 2) * 2 + hd] = s2; als[(row0 + 3) * 2 + hd] = s3;
    ald[(row0 + 0) * 2 + hd] = d0; ald[(row0 + 1) * 2 + hd] = d1;
    ald[(row0 + 2) * 2 + hd] = d2; ald[(row0 + 3) * 2 + hd] = d3;
  }
}

// fused leaky-softmax-aggregate: one wave per node; lane carries channels
// 2*lane, 2*lane+1 (float2). Lanes 0-31 = head 0, 32-63 = head 1.
// Online softmax with 1-deep prefetch of (s, als2, h).
__global__ __launch_bounds__(256) void fused_agg(const int* __restrict__ rowptr,
                                                 const int* __restrict__ csr_src,
                                                 const float* __restrict__ Hf,
                                                 const float* __restrict__ als,
                                                 const float* __restrict__ ald,
                                                 float* __restrict__ A) {
  int n = (blockIdx.x * 256 + threadIdx.x) >> 6;
  int lane = threadIdx.x & 63;
  if (n >= N_NODES) return;
  int beg = rowptr[n], end = rowptr[n + 1];
  float2 adv = ((const float2*)ald)[n];

  int s = csr_src[beg];
  float2 al = ((const float2*)als)[s];
  float2 h  = *(const float2*)(Hf + (size_t)s * FDIM + lane * 2);

  float m = -__builtin_inff(), l = 0.f;
  float ox = 0.f, oy = 0.f;
  for (int j = beg; j < end; ++j) {
    // prefetch next edge
    int jn = (j + 1 < end) ? j + 1 : j;
    int s2 = csr_src[jn];
    float2 al2 = ((const float2*)als)[s2];
    float2 h2  = *(const float2*)(Hf + (size_t)s2 * FDIM + lane * 2);

    float v0 = al.x + adv.x; v0 = v0 > 0.f ? v0 : SLOPE * v0;
    float v1 = al.y + adv.y; v1 = v1 > 0.f ? v1 : SLOPE * v1;
    float v = (lane >= 32) ? v1 : v0;
    float nm = fmaxf(m, v);
    float sc = __expf(m - nm);   // first iter: exp(-inf) = 0
    float ex = __expf(v - nm);
    l  = fmaf(l,  sc, ex);
    ox = fmaf(ox, sc, ex * h.x);
    oy = fmaf(oy, sc, ex * h.y);
    m = nm;
    al = al2; h = h2;
  }
  float inv = 1.f / (l + 1e-16f);
  float2 outv = {ox * inv, oy * inv};
  *(float2*)(A + (size_t)n * FDIM + lane * 2) = outv;
}

// per-channel sum / sumsq over N rows.
__global__ __launch_bounds__(256) void bn_stats(const float* __restrict__ A,
                                                float* __restrict__ acc) {
  __shared__ float sh[512];
  int tid = threadIdx.x;
  float s = 0.f, q = 0.f;
  for (int i = blockIdx.x * 256 + tid; i < N_NODES * FDIM; i += gridDim.x * 256) {
    float v = A[i];
    s += v;
    q = fmaf(v, v, q);
  }
  sh[tid] = s;
  sh[256 + tid] = q;
  __syncthreads();
  if (tid < 128) {
    atomicAdd(&acc[tid],       sh[tid] + sh[tid + 128]);
    atomicAdd(&acc[128 + tid], sh[256 + tid] + sh[256 + tid + 128]);
  }
}

__global__ __launch_bounds__(256) void bn_apply(float* __restrict__ A,
                                                const float* __restrict__ acc,
                                                const float* __restrict__ g,
                                                const float* __restrict__ be) {
  int i = blockIdx.x * 256 + threadIdx.x;
  if (i >= N_NODES * FDIM) return;
  int c = i & 127;
  float mu  = acc[c] * (1.f / N_NODES);
  float var = acc[128 + c] * (1.f / N_NODES) - mu * mu;
  float v = (A[i] - mu) * rsqrtf(var + BN_EPS) * g[c] + be[c];
  A[i] = v > 0.f ? v : 0.f;
}

__global__ __launch_bounds__(256) void head_mean(const float* __restrict__ A,
                                                 const float* __restrict__ b2,
                                                 float* __restrict__ out) {
  int i = blockIdx.x * 256 + threadIdx.x;
  if (i >= N_NODES * 64) return;
  int n = i >> 6, c = i & 63;
  out[i] = 0.5f * (A[(size_t)n * FDIM + c] + A[(size_t)n * FDIM + 64 + c]) + b2[c];
}

extern "C" void kernel_launch(void* const* d_in, const int* in_sizes, int n_in,
                              void* d_out, int out_size, void* d_ws, size_t ws_size,
                              hipStream_t stream) {
  const float* x  = (const float*)d_in[0];
  const int*   ei = (const int*)d_in[1];          // [2, E] int32
  const int* src = ei;
  const int* dst = ei + N_EDGES;

  const float* W[3]    = {(const float*)d_in[2],  (const float*)d_in[8],  (const float*)d_in[14]};
  const float* asrc[3] = {(const float*)d_in[3],  (const float*)d_in[9],  (const float*)d_in[15]};
  const float* adst[3] = {(const float*)d_in[4],  (const float*)d_in[10], (const float*)d_in[16]};
  const float* g[2]    = {(const float*)d_in[6],  (const float*)d_in[12]};
  const float* be[2]   = {(const float*)d_in[7],  (const float*)d_in[13]};
  const float* b2      = (const float*)d_in[17];

  // workspace layout (4-byte units), offsets kept multiples of 4 so that
  // float2/float4 accesses stay 16B-aligned:
  // counts 50000 | rowptr 50004 | fill 50000 | csr ET | bna 256 | als 2N | ald 2N | H 128N | A 128N
  int*   counts  = (int*)d_ws;
  int*   rowptr  = counts + 50000;
  int*   fill    = rowptr + 50004;
  int*   csr_src = fill + 50000;
  float* bna     = (float*)(csr_src + ET);
  float* als     = bna + 256;
  float* ald     = als + (size_t)N_NODES * 2;
  float* Hbuf    = ald + (size_t)N_NODES * 2;
  float* A       = Hbuf + (size_t)N_NODES * FDIM;

  // ---- build CSR (edges identical across layers) ----
  hipMemsetAsync(counts, 0, (size_t)N_NODES * sizeof(int), stream);
  hist_kernel<<<(ET + 255) / 256, 256, 0, stream>>>(dst, counts);
  scan_kernel<<<1, 1024, 0, stream>>>(counts, rowptr, fill);
  scatter_kernel<<<(ET + 255) / 256, 256, 0, stream>>>(src, dst, fill, csr_src);

  for (int L = 0; L < 3; ++L) {
    const float* fin = (L == 0) ? x : A;
    gemm128<<<N_NODES / 8, 256, 0, stream>>>(fin, W[L], asrc[L], adst[L], Hbuf, als, ald);
    fused_agg<<<(N_NODES * 64 + 255) / 256, 256, 0, stream>>>(rowptr, csr_src, Hbuf, als, ald, A);
    if (L < 2) {
      hipMemsetAsync(bna, 0, 256 * sizeof(float), stream);
      bn_stats<<<1024, 256, 0, stream>>>(A, bna);
      bn_apply<<<(N_NODES * FDIM + 255) / 256, 256, 0, stream>>>(A, bna, g[L], be[L]);
    } else {
      head_mean<<<(N_NODES * 64 + 255) / 256, 256, 0, stream>>>(A, b2, (float*)d_out);
    }
  }
}

// Round 4
// 721.081 us; speedup vs baseline: 2.6570x; 1.5004x over previous
//
#include <hip/hip_runtime.h>

// GAT 3-layer (N=50000, E=800000 (+N self loops), H=2, C=64, widths 128)
// Round 4: bf16 MFMA gemm (BN+ReLU fused prologue, att-logit epilogue, bf16 H
// output), fused_agg gathers bf16 rows + layer-2 head-mean fused.

#define N_NODES 50000
#define N_EDGES 800000
#define ET (N_EDGES + N_NODES)   // 850000 incl self loops
#define FDIM 128
#define SLOPE 0.2f
#define BN_EPS 1e-5f

typedef __attribute__((ext_vector_type(8))) short bf16x8;
typedef __attribute__((ext_vector_type(4))) float f32x4;
typedef __attribute__((ext_vector_type(8))) unsigned short u16x8;

__device__ __forceinline__ unsigned short f2bf(float f) {
  unsigned u = __float_as_uint(f);
  u = u + 0x7fffu + ((u >> 16) & 1u);   // RNE
  return (unsigned short)(u >> 16);
}

// ---------------- CSR build ----------------

__global__ __launch_bounds__(256) void hist_kernel(const int* __restrict__ dst,
                                                   int* __restrict__ counts) {
  int i = blockIdx.x * 256 + threadIdx.x;
  if (i >= ET) return;
  int d = (i < N_EDGES) ? dst[i] : i - N_EDGES;
  atomicAdd(&counts[d], 1);
}

__global__ __launch_bounds__(1024) void scan_kernel(const int* __restrict__ counts,
                                                    int* __restrict__ rowptr,
                                                    int* __restrict__ fill) {
  __shared__ int sums[1024];
  int t = threadIdx.x;
  const int CH = (N_NODES + 1023) / 1024;   // 49
  int base = t * CH;
  int s = 0;
  for (int i = 0; i < CH; ++i) {
    int idx = base + i;
    if (idx < N_NODES) s += counts[idx];
  }
  sums[t] = s;
  __syncthreads();
  for (int off = 1; off < 1024; off <<= 1) {
    int v = (t >= off) ? sums[t - off] : 0;
    __syncthreads();
    sums[t] += v;
    __syncthreads();
  }
  int run = (t == 0) ? 0 : sums[t - 1];
  for (int i = 0; i < CH; ++i) {
    int idx = base + i;
    if (idx < N_NODES) {
      rowptr[idx] = run;
      fill[idx] = run;
      run += counts[idx];
    }
  }
  if (t == 1023) rowptr[N_NODES] = run;   // == ET
}

__global__ __launch_bounds__(256) void scatter_kernel(const int* __restrict__ src,
                                                      const int* __restrict__ dst,
                                                      int* __restrict__ fill,
                                                      int* __restrict__ csr_src) {
  int i = blockIdx.x * 256 + threadIdx.x;
  if (i >= ET) return;
  int s, d;
  if (i < N_EDGES) { s = src[i]; d = dst[i]; } else { s = d = i - N_EDGES; }
  int pos = atomicAdd(&fill[d], 1);
  csr_src[pos] = s;
}

// ---------------- W repack: all 3 layers -> B-fragment order, bf16 ----------------
// Wr[L][((t*4+ks)*64+lane)*8+j] = bf16( W[L][k][col] ),
//   k = ks*32 + (lane>>4)*8 + j, col = t*16 + (lane&15)
__global__ __launch_bounds__(256) void repack_w(const float* __restrict__ W0,
                                                const float* __restrict__ W1,
                                                const float* __restrict__ W2,
                                                unsigned short* __restrict__ Wr) {
  int i = blockIdx.x * 256 + threadIdx.x;
  if (i >= 3 * 16384) return;
  int L = i >> 14, rem = i & 16383;
  int t  = rem >> 11;
  int ks = (rem >> 9) & 3;
  int ln = (rem >> 3) & 63;
  int j  = rem & 7;
  int k   = ks * 32 + (ln >> 4) * 8 + j;
  int col = t * 16 + (ln & 15);
  const float* W = (L == 0) ? W0 : ((L == 1) ? W1 : W2);
  Wr[i] = f2bf(W[k * 128 + col]);
}

// ---------------- MFMA gemm + BN/ReLU prologue + att-logit epilogue ----------------
// block = 256 (4 waves); wave computes rows [blk*64+wv*16, +16) x all 128 cols.
// Xin fp32 [N,128]; if doBN: x = relu((x-mu)*rsqrt(var+eps)*g + be) using bna sums.
// Outputs: Hbf bf16 [N,128], als/ald fp32 [N,2].
__global__ __launch_bounds__(256) void gemm_mfma(const float* __restrict__ Xin,
                                                 const unsigned short* __restrict__ WrL,
                                                 const float* __restrict__ bna,
                                                 const float* __restrict__ g,
                                                 const float* __restrict__ be,
                                                 const float* __restrict__ a_src,
                                                 const float* __restrict__ a_dst,
                                                 unsigned short* __restrict__ Hbf,
                                                 float* __restrict__ als,
                                                 float* __restrict__ ald,
                                                 int doBN) {
  __shared__ unsigned short lds[4][16][128];
  int lane = threadIdx.x & 63;
  int wv   = threadIdx.x >> 6;
  int row0 = blockIdx.x * 64 + wv * 16;
  int gidx = lane & 15;
  int quad = lane >> 4;
  int rA   = row0 + gidx;
  int rAc  = rA < N_NODES ? rA : N_NODES - 1;
  int koff = quad * 8;

  f32x4 acc[8] = {};
#pragma unroll
  for (int ks = 0; ks < 4; ++ks) {
    int cb = ks * 32 + koff;
    const float4* xr = (const float4*)(Xin + (size_t)rAc * FDIM + cb);
    float4 xa = xr[0], xb = xr[1];
    float xv[8] = {xa.x, xa.y, xa.z, xa.w, xb.x, xb.y, xb.z, xb.w};
    bf16x8 afrag;
    if (doBN) {
#pragma unroll
      for (int j = 0; j < 8; ++j) {
        int c = cb + j;
        float mu  = bna[c] * (1.f / N_NODES);
        float var = bna[128 + c] * (1.f / N_NODES) - mu * mu;
        float v = (xv[j] - mu) * rsqrtf(var + BN_EPS) * g[c] + be[c];
        v = v > 0.f ? v : 0.f;
        afrag[j] = (short)f2bf(v);
      }
    } else {
#pragma unroll
      for (int j = 0; j < 8; ++j) afrag[j] = (short)f2bf(xv[j]);
    }
#pragma unroll
    for (int t = 0; t < 8; ++t) {
      bf16x8 bfrag = *(const bf16x8*)(WrL + ((size_t)((t * 4 + ks) * 64 + lane)) * 8);
      acc[t] = __builtin_amdgcn_mfma_f32_16x16x32_bf16(afrag, bfrag, acc[t], 0, 0, 0);
    }
  }

  // ---- attention-logit epilogue ----
  // lane holds D[row=(quad*4+r)][col=t*16+gidx]
  float vs[2][4] = {}, vd[2][4] = {};
#pragma unroll
  for (int t = 0; t < 8; ++t) {
    int col = t * 16 + gidx;
    float as = a_src[col], ad = a_dst[col];
    int hd = t >> 2;
#pragma unroll
    for (int r = 0; r < 4; ++r) {
      vs[hd][r] = fmaf(acc[t][r], as, vs[hd][r]);
      vd[hd][r] = fmaf(acc[t][r], ad, vd[hd][r]);
    }
  }
#pragma unroll
  for (int off = 1; off < 16; off <<= 1) {
#pragma unroll
    for (int hd = 0; hd < 2; ++hd)
#pragma unroll
      for (int r = 0; r < 4; ++r) {
        vs[hd][r] += __shfl_xor(vs[hd][r], off);
        vd[hd][r] += __shfl_xor(vd[hd][r], off);
      }
  }
  if (gidx == 0) {
#pragma unroll
    for (int r = 0; r < 4; ++r) {
      int row = row0 + quad * 4 + r;
      if (row < N_NODES) {
        als[row * 2 + 0] = vs[0][r]; als[row * 2 + 1] = vs[1][r];
        ald[row * 2 + 0] = vd[0][r]; ald[row * 2 + 1] = vd[1][r];
      }
    }
  }

  // ---- bf16 H store via LDS transpose ----
#pragma unroll
  for (int t = 0; t < 8; ++t)
#pragma unroll
    for (int r = 0; r < 4; ++r)
      lds[wv][quad * 4 + r][t * 16 + gidx] = f2bf(acc[t][r]);
  __syncthreads();
#pragma unroll
  for (int it = 0; it < 4; ++it) {
    int rloc = it * 4 + quad;
    int row = row0 + rloc;
    if (row < N_NODES)
      *(u16x8*)(Hbf + (size_t)row * FDIM + gidx * 8) = *(u16x8*)&lds[wv][rloc][gidx * 8];
  }
}

// ---------------- fused leaky-softmax-aggregate ----------------
// one wave per node; lane carries channels 2*lane, 2*lane+1 (bf16 pair = uint).
// Lanes 0-31 = head 0, 32-63 = head 1. mode==0: write A fp32 [N,128];
// mode==2: head-mean + b2 -> out fp32 [N,64].
__global__ __launch_bounds__(256) void fused_agg(const int* __restrict__ rowptr,
                                                 const int* __restrict__ csr_src,
                                                 const unsigned* __restrict__ H2,
                                                 const float* __restrict__ als,
                                                 const float* __restrict__ ald,
                                                 float* __restrict__ A,
                                                 float* __restrict__ out,
                                                 const float* __restrict__ b2,
                                                 int mode) {
  int n = (blockIdx.x * 256 + threadIdx.x) >> 6;
  int lane = threadIdx.x & 63;
  if (n >= N_NODES) return;
  int beg = rowptr[n], end = rowptr[n + 1];
  float2 adv = ((const float2*)ald)[n];

  int s = csr_src[beg];
  float2 al = ((const float2*)als)[s];
  unsigned hp = H2[(size_t)s * 64 + lane];

  float m = -__builtin_inff(), l = 0.f;
  float ox = 0.f, oy = 0.f;
  for (int j = beg; j < end; ++j) {
    int jn = (j + 1 < end) ? j + 1 : j;
    int s2 = csr_src[jn];
    float2 al2 = ((const float2*)als)[s2];
    unsigned hp2 = H2[(size_t)s2 * 64 + lane];

    float v0 = al.x + adv.x; v0 = v0 > 0.f ? v0 : SLOPE * v0;
    float v1 = al.y + adv.y; v1 = v1 > 0.f ? v1 : SLOPE * v1;
    float v = (lane >= 32) ? v1 : v0;
    float hx = __uint_as_float(hp << 16);
    float hy = __uint_as_float(hp & 0xffff0000u);
    float nm = fmaxf(m, v);
    float sc = __expf(m - nm);   // first iter: exp(-inf) = 0
    float ex = __expf(v - nm);
    l  = fmaf(l,  sc, ex);
    ox = fmaf(ox, sc, ex * hx);
    oy = fmaf(oy, sc, ex * hy);
    m = nm;
    al = al2; hp = hp2;
  }
  float inv = 1.f / (l + 1e-16f);
  ox *= inv; oy *= inv;
  if (mode == 0) {
    float2 outv = {ox, oy};
    *(float2*)(A + (size_t)n * FDIM + lane * 2) = outv;
  } else {
    float px = __shfl_xor(ox, 32);
    float py = __shfl_xor(oy, 32);
    if (lane < 32) {
      int c = lane * 2;
      float2 outv = {0.5f * (ox + px) + b2[c], 0.5f * (oy + py) + b2[c + 1]};
      *(float2*)(out + (size_t)n * 64 + c) = outv;
    }
  }
}

// per-channel sum / sumsq over N rows of A.
__global__ __launch_bounds__(256) void bn_stats(const float* __restrict__ A,
                                                float* __restrict__ acc) {
  __shared__ float sh[512];
  int tid = threadIdx.x;
  float s = 0.f, q = 0.f;
  for (int i = blockIdx.x * 256 + tid; i < N_NODES * FDIM; i += gridDim.x * 256) {
    float v = A[i];
    s += v;
    q = fmaf(v, v, q);
  }
  sh[tid] = s;
  sh[256 + tid] = q;
  __syncthreads();
  if (tid < 128) {
    atomicAdd(&acc[tid],       sh[tid] + sh[tid + 128]);
    atomicAdd(&acc[128 + tid], sh[256 + tid] + sh[256 + tid + 128]);
  }
}

extern "C" void kernel_launch(void* const* d_in, const int* in_sizes, int n_in,
                              void* d_out, int out_size, void* d_ws, size_t ws_size,
                              hipStream_t stream) {
  const float* x  = (const float*)d_in[0];
  const int*   ei = (const int*)d_in[1];
  const int* src = ei;
  const int* dst = ei + N_EDGES;

  const float* W[3]    = {(const float*)d_in[2],  (const float*)d_in[8],  (const float*)d_in[14]};
  const float* asrc[3] = {(const float*)d_in[3],  (const float*)d_in[9],  (const float*)d_in[15]};
  const float* adst[3] = {(const float*)d_in[4],  (const float*)d_in[10], (const float*)d_in[16]};
  const float* g[2]    = {(const float*)d_in[6],  (const float*)d_in[12]};
  const float* be[2]   = {(const float*)d_in[7],  (const float*)d_in[13]};
  const float* b2      = (const float*)d_in[17];

  // workspace (4-byte units, every region 16B-aligned):
  // counts 50048 | rowptr 50048 | fill 50048 | csr 850048 | bna 256 |
  // als 100096 | ald 100096 | Wr 24576 (3*16384 u16) | Hbf 3.2M (6.4M u16) | A 6.4M f32
  int*   counts  = (int*)d_ws;
  int*   rowptr  = counts + 50048;
  int*   fill    = rowptr + 50048;
  int*   csr_src = fill + 50048;
  float* bna     = (float*)(csr_src + 850048);
  float* als     = bna + 256;
  float* ald     = als + 100096;
  unsigned short* Wr  = (unsigned short*)(ald + 100096);
  unsigned short* Hbf = Wr + 3 * 16384;
  float* A       = (float*)(Hbf + (size_t)N_NODES * FDIM);

  // ---- build CSR + repack W (edge set / weights constant across layers) ----
  hipMemsetAsync(counts, 0, (size_t)N_NODES * sizeof(int), stream);
  hist_kernel<<<(ET + 255) / 256, 256, 0, stream>>>(dst, counts);
  scan_kernel<<<1, 1024, 0, stream>>>(counts, rowptr, fill);
  scatter_kernel<<<(ET + 255) / 256, 256, 0, stream>>>(src, dst, fill, csr_src);
  repack_w<<<(3 * 16384 + 255) / 256, 256, 0, stream>>>(W[0], W[1], W[2], Wr);

  const int gemm_grid = (N_NODES + 63) / 64;
  const int agg_grid  = (N_NODES * 64 + 255) / 256;

  for (int L = 0; L < 3; ++L) {
    const float* fin = (L == 0) ? x : A;
    int doBN = (L > 0);
    const float* gg = doBN ? g[L - 1]  : (const float*)nullptr;
    const float* bb = doBN ? be[L - 1] : (const float*)nullptr;
    gemm_mfma<<<gemm_grid, 256, 0, stream>>>(fin, Wr + (size_t)L * 16384, bna, gg, bb,
                                             asrc[L], adst[L], Hbf, als, ald, doBN);
    fused_agg<<<agg_grid, 256, 0, stream>>>(rowptr, csr_src, (const unsigned*)Hbf,
                                            als, ald, A, (float*)d_out, b2,
                                            (L == 2) ? 2 : 0);
    if (L < 2) {
      hipMemsetAsync(bna, 0, 256 * sizeof(float), stream);
      bn_stats<<<1024, 256, 0, stream>>>(A, bna);
    }
  }
}

// Round 5
// 483.255 us; speedup vs baseline: 3.9645x; 1.4921x over previous
//
#include <hip/hip_runtime.h>

// GAT 3-layer (N=50000, E=800000 (+N self loops), H=2, C=64, widths 128)
// Round 5: parallel 3-phase CSR scan (R4's single-block scan was 127us, 18%
// of total); fused_agg unrolled 2 edges/iter (paired online-softmax update).

#define N_NODES 50000
#define N_EDGES 800000
#define ET (N_EDGES + N_NODES)   // 850000 incl self loops
#define FDIM 128
#define SLOPE 0.2f
#define BN_EPS 1e-5f
#define SCAN_NB 196              // ceil(50000/256)

typedef __attribute__((ext_vector_type(8))) short bf16x8;
typedef __attribute__((ext_vector_type(4))) float f32x4;
typedef __attribute__((ext_vector_type(8))) unsigned short u16x8;

__device__ __forceinline__ unsigned short f2bf(float f) {
  unsigned u = __float_as_uint(f);
  u = u + 0x7fffu + ((u >> 16) & 1u);   // RNE
  return (unsigned short)(u >> 16);
}

// ---------------- CSR build ----------------

__global__ __launch_bounds__(256) void hist_kernel(const int* __restrict__ dst,
                                                   int* __restrict__ counts) {
  int i = blockIdx.x * 256 + threadIdx.x;
  if (i >= ET) return;
  int d = (i < N_EDGES) ? dst[i] : i - N_EDGES;
  atomicAdd(&counts[d], 1);
}

// phase 1: per-block exclusive scan (wave shfl scans + LDS wave sums),
// writes local-exclusive values to rowptr and block totals to partials.
__global__ __launch_bounds__(256) void scan_blk(const int* __restrict__ counts,
                                                int* __restrict__ rowptr,
                                                int* __restrict__ partials) {
  int i = blockIdx.x * 256 + threadIdx.x;
  int lane = threadIdx.x & 63, wv = threadIdx.x >> 6;
  int c = (i < N_NODES) ? counts[i] : 0;
  int v = c;
#pragma unroll
  for (int off = 1; off < 64; off <<= 1) {
    int u = __shfl_up(v, off);
    if (lane >= off) v += u;
  }
  __shared__ int wsum[4];
  if (lane == 63) wsum[wv] = v;
  __syncthreads();
  int add = 0;
  for (int w = 0; w < wv; ++w) add += wsum[w];
  if (i < N_NODES) rowptr[i] = v - c + add;
  if (threadIdx.x == 255) partials[blockIdx.x] = add + v;
}

// phase 2: exclusive scan of the SCAN_NB block totals (single small block)
__global__ __launch_bounds__(256) void scan_top(int* __restrict__ partials) {
  int t = threadIdx.x;
  int lane = t & 63, wv = t >> 6;
  int c = (t < SCAN_NB) ? partials[t] : 0;
  int v = c;
#pragma unroll
  for (int off = 1; off < 64; off <<= 1) {
    int u = __shfl_up(v, off);
    if (lane >= off) v += u;
  }
  __shared__ int wsum[4];
  if (lane == 63) wsum[wv] = v;
  __syncthreads();
  int add = 0;
  for (int w = 0; w < wv; ++w) add += wsum[w];
  if (t < SCAN_NB) partials[t] = v - c + add;
}

// phase 3: add block offsets; produce final rowptr + fill copy
__global__ __launch_bounds__(256) void scan_fin(int* __restrict__ rowptr,
                                                const int* __restrict__ partials,
                                                int* __restrict__ fill) {
  int i = blockIdx.x * 256 + threadIdx.x;
  if (i >= N_NODES) return;
  int v = rowptr[i] + partials[blockIdx.x];
  rowptr[i] = v;
  fill[i] = v;
  if (i == 0) rowptr[N_NODES] = ET;   // total is a compile-time constant
}

__global__ __launch_bounds__(256) void scatter_kernel(const int* __restrict__ src,
                                                      const int* __restrict__ dst,
                                                      int* __restrict__ fill,
                                                      int* __restrict__ csr_src) {
  int i = blockIdx.x * 256 + threadIdx.x;
  if (i >= ET) return;
  int s, d;
  if (i < N_EDGES) { s = src[i]; d = dst[i]; } else { s = d = i - N_EDGES; }
  int pos = atomicAdd(&fill[d], 1);
  csr_src[pos] = s;
}

// ---------------- W repack: all 3 layers -> B-fragment order, bf16 ----------------
__global__ __launch_bounds__(256) void repack_w(const float* __restrict__ W0,
                                                const float* __restrict__ W1,
                                                const float* __restrict__ W2,
                                                unsigned short* __restrict__ Wr) {
  int i = blockIdx.x * 256 + threadIdx.x;
  if (i >= 3 * 16384) return;
  int L = i >> 14, rem = i & 16383;
  int t  = rem >> 11;
  int ks = (rem >> 9) & 3;
  int ln = (rem >> 3) & 63;
  int j  = rem & 7;
  int k   = ks * 32 + (ln >> 4) * 8 + j;
  int col = t * 16 + (ln & 15);
  const float* W = (L == 0) ? W0 : ((L == 1) ? W1 : W2);
  Wr[i] = f2bf(W[k * 128 + col]);
}

// ---------------- MFMA gemm + BN/ReLU prologue + att-logit epilogue ----------------
__global__ __launch_bounds__(256) void gemm_mfma(const float* __restrict__ Xin,
                                                 const unsigned short* __restrict__ WrL,
                                                 const float* __restrict__ bna,
                                                 const float* __restrict__ g,
                                                 const float* __restrict__ be,
                                                 const float* __restrict__ a_src,
                                                 const float* __restrict__ a_dst,
                                                 unsigned short* __restrict__ Hbf,
                                                 float* __restrict__ als,
                                                 float* __restrict__ ald,
                                                 int doBN) {
  __shared__ unsigned short lds[4][16][128];
  int lane = threadIdx.x & 63;
  int wv   = threadIdx.x >> 6;
  int row0 = blockIdx.x * 64 + wv * 16;
  int gidx = lane & 15;
  int quad = lane >> 4;
  int rA   = row0 + gidx;
  int rAc  = rA < N_NODES ? rA : N_NODES - 1;
  int koff = quad * 8;

  f32x4 acc[8] = {};
#pragma unroll
  for (int ks = 0; ks < 4; ++ks) {
    int cb = ks * 32 + koff;
    const float4* xr = (const float4*)(Xin + (size_t)rAc * FDIM + cb);
    float4 xa = xr[0], xb = xr[1];
    float xv[8] = {xa.x, xa.y, xa.z, xa.w, xb.x, xb.y, xb.z, xb.w};
    bf16x8 afrag;
    if (doBN) {
#pragma unroll
      for (int j = 0; j < 8; ++j) {
        int c = cb + j;
        float mu  = bna[c] * (1.f / N_NODES);
        float var = bna[128 + c] * (1.f / N_NODES) - mu * mu;
        float v = (xv[j] - mu) * rsqrtf(var + BN_EPS) * g[c] + be[c];
        v = v > 0.f ? v : 0.f;
        afrag[j] = (short)f2bf(v);
      }
    } else {
#pragma unroll
      for (int j = 0; j < 8; ++j) afrag[j] = (short)f2bf(xv[j]);
    }
#pragma unroll
    for (int t = 0; t < 8; ++t) {
      bf16x8 bfrag = *(const bf16x8*)(WrL + ((size_t)((t * 4 + ks) * 64 + lane)) * 8);
      acc[t] = __builtin_amdgcn_mfma_f32_16x16x32_bf16(afrag, bfrag, acc[t], 0, 0, 0);
    }
  }

  // ---- attention-logit epilogue: lane holds D[row=(quad*4+r)][col=t*16+gidx]
  float vs[2][4] = {}, vd[2][4] = {};
#pragma unroll
  for (int t = 0; t < 8; ++t) {
    int col = t * 16 + gidx;
    float as = a_src[col], ad = a_dst[col];
    int hd = t >> 2;
#pragma unroll
    for (int r = 0; r < 4; ++r) {
      vs[hd][r] = fmaf(acc[t][r], as, vs[hd][r]);
      vd[hd][r] = fmaf(acc[t][r], ad, vd[hd][r]);
    }
  }
#pragma unroll
  for (int off = 1; off < 16; off <<= 1) {
#pragma unroll
    for (int hd = 0; hd < 2; ++hd)
#pragma unroll
      for (int r = 0; r < 4; ++r) {
        vs[hd][r] += __shfl_xor(vs[hd][r], off);
        vd[hd][r] += __shfl_xor(vd[hd][r], off);
      }
  }
  if (gidx == 0) {
#pragma unroll
    for (int r = 0; r < 4; ++r) {
      int row = row0 + quad * 4 + r;
      if (row < N_NODES) {
        als[row * 2 + 0] = vs[0][r]; als[row * 2 + 1] = vs[1][r];
        ald[row * 2 + 0] = vd[0][r]; ald[row * 2 + 1] = vd[1][r];
      }
    }
  }

  // ---- bf16 H store via LDS transpose ----
#pragma unroll
  for (int t = 0; t < 8; ++t)
#pragma unroll
    for (int r = 0; r < 4; ++r)
      lds[wv][quad * 4 + r][t * 16 + gidx] = f2bf(acc[t][r]);
  __syncthreads();
#pragma unroll
  for (int it = 0; it < 4; ++it) {
    int rloc = it * 4 + quad;
    int row = row0 + rloc;
    if (row < N_NODES)
      *(u16x8*)(Hbf + (size_t)row * FDIM + gidx * 8) = *(u16x8*)&lds[wv][rloc][gidx * 8];
  }
}

// ---------------- fused leaky-softmax-aggregate, 2 edges/iter ----------------
// one wave per node; lane carries channels 2*lane, 2*lane+1 (bf16 pair = u32).
// Lanes 0-31 = head 0, 32-63 = head 1. mode 0: A fp32 [N,128];
// mode 2: head-mean + b2 -> out fp32 [N,64].
__global__ __launch_bounds__(256) void fused_agg(const int* __restrict__ rowptr,
                                                 const int* __restrict__ csr_src,
                                                 const unsigned* __restrict__ H2,
                                                 const float* __restrict__ als,
                                                 const float* __restrict__ ald,
                                                 float* __restrict__ A,
                                                 float* __restrict__ out,
                                                 const float* __restrict__ b2,
                                                 int mode) {
  int n = (blockIdx.x * 256 + threadIdx.x) >> 6;
  int lane = threadIdx.x & 63;
  if (n >= N_NODES) return;
  int beg = rowptr[n], end = rowptr[n + 1];
  float2 adv = ((const float2*)ald)[n];
  float advh = (lane >= 32) ? adv.y : adv.x;

  // prime pair (deg >= 1 always: self loop)
  int s0 = csr_src[beg];
  int s1 = csr_src[(beg + 1 < end) ? beg + 1 : beg];
  float2 al0 = ((const float2*)als)[s0];
  float2 al1 = ((const float2*)als)[s1];
  unsigned h0 = H2[(size_t)s0 * 64 + lane];
  unsigned h1 = H2[(size_t)s1 * 64 + lane];

  float m = -__builtin_inff(), l = 0.f;
  float ox = 0.f, oy = 0.f;
  int j = beg;
  for (; j + 2 <= end; j += 2) {
    // prefetch next pair
    int jn0 = (j + 2 < end) ? j + 2 : end - 1;
    int jn1 = (j + 3 < end) ? j + 3 : end - 1;
    int t0 = csr_src[jn0], t1 = csr_src[jn1];
    float2 an0 = ((const float2*)als)[t0];
    float2 an1 = ((const float2*)als)[t1];
    unsigned hn0 = H2[(size_t)t0 * 64 + lane];
    unsigned hn1 = H2[(size_t)t1 * 64 + lane];

    float va = ((lane >= 32) ? al0.y : al0.x) + advh; va = va > 0.f ? va : SLOPE * va;
    float vb = ((lane >= 32) ? al1.y : al1.x) + advh; vb = vb > 0.f ? vb : SLOPE * vb;
    float nm = fmaxf(m, fmaxf(va, vb));
    float sc = __expf(m - nm);          // first iter: exp(-inf)=0
    float ea = __expf(va - nm);
    float eb = __expf(vb - nm);
    float h0x = __uint_as_float(h0 << 16), h0y = __uint_as_float(h0 & 0xffff0000u);
    float h1x = __uint_as_float(h1 << 16), h1y = __uint_as_float(h1 & 0xffff0000u);
    l  = fmaf(l,  sc, ea + eb);
    ox = fmaf(ox, sc, fmaf(ea, h0x, eb * h1x));
    oy = fmaf(oy, sc, fmaf(ea, h0y, eb * h1y));
    m = nm;
    al0 = an0; al1 = an1; h0 = hn0; h1 = hn1;
  }
  if (j < end) {   // odd leftover; its data is already in al0/h0
    float va = ((lane >= 32) ? al0.y : al0.x) + advh; va = va > 0.f ? va : SLOPE * va;
    float nm = fmaxf(m, va);
    float sc = __expf(m - nm);
    float ea = __expf(va - nm);
    float h0x = __uint_as_float(h0 << 16), h0y = __uint_as_float(h0 & 0xffff0000u);
    l  = fmaf(l,  sc, ea);
    ox = fmaf(ox, sc, ea * h0x);
    oy = fmaf(oy, sc, ea * h0y);
  }
  float inv = 1.f / (l + 1e-16f);
  ox *= inv; oy *= inv;
  if (mode == 0) {
    float2 outv = {ox, oy};
    *(float2*)(A + (size_t)n * FDIM + lane * 2) = outv;
  } else {
    float px = __shfl_xor(ox, 32);
    float py = __shfl_xor(oy, 32);
    if (lane < 32) {
      int c = lane * 2;
      float2 outv = {0.5f * (ox + px) + b2[c], 0.5f * (oy + py) + b2[c + 1]};
      *(float2*)(out + (size_t)n * 64 + c) = outv;
    }
  }
}

// per-channel sum / sumsq over N rows of A.
__global__ __launch_bounds__(256) void bn_stats(const float* __restrict__ A,
                                                float* __restrict__ acc) {
  __shared__ float sh[512];
  int tid = threadIdx.x;
  float s = 0.f, q = 0.f;
  for (int i = blockIdx.x * 256 + tid; i < N_NODES * FDIM; i += gridDim.x * 256) {
    float v = A[i];
    s += v;
    q = fmaf(v, v, q);
  }
  sh[tid] = s;
  sh[256 + tid] = q;
  __syncthreads();
  if (tid < 128) {
    atomicAdd(&acc[tid],       sh[tid] + sh[tid + 128]);
    atomicAdd(&acc[128 + tid], sh[256 + tid] + sh[256 + tid + 128]);
  }
}

extern "C" void kernel_launch(void* const* d_in, const int* in_sizes, int n_in,
                              void* d_out, int out_size, void* d_ws, size_t ws_size,
                              hipStream_t stream) {
  const float* x  = (const float*)d_in[0];
  const int*   ei = (const int*)d_in[1];
  const int* src = ei;
  const int* dst = ei + N_EDGES;

  const float* W[3]    = {(const float*)d_in[2],  (const float*)d_in[8],  (const float*)d_in[14]};
  const float* asrc[3] = {(const float*)d_in[3],  (const float*)d_in[9],  (const float*)d_in[15]};
  const float* adst[3] = {(const float*)d_in[4],  (const float*)d_in[10], (const float*)d_in[16]};
  const float* g[2]    = {(const float*)d_in[6],  (const float*)d_in[12]};
  const float* be[2]   = {(const float*)d_in[7],  (const float*)d_in[13]};
  const float* b2      = (const float*)d_in[17];

  // workspace (4-byte units, every region 16B-aligned):
  int*   counts   = (int*)d_ws;
  int*   rowptr   = counts + 50048;
  int*   fill     = rowptr + 50048;
  int*   partials = fill + 50048;
  int*   csr_src  = partials + 256;
  float* bna      = (float*)(csr_src + 850048);
  float* als      = bna + 256;
  float* ald      = als + 100096;
  unsigned short* Wr  = (unsigned short*)(ald + 100096);
  unsigned short* Hbf = Wr + 3 * 16384;
  float* A        = (float*)(Hbf + (size_t)N_NODES * FDIM);

  // ---- build CSR + repack W (edge set / weights constant across layers) ----
  hipMemsetAsync(counts, 0, (size_t)N_NODES * sizeof(int), stream);
  hist_kernel<<<(ET + 255) / 256, 256, 0, stream>>>(dst, counts);
  scan_blk<<<SCAN_NB, 256, 0, stream>>>(counts, rowptr, partials);
  scan_top<<<1, 256, 0, stream>>>(partials);
  scan_fin<<<SCAN_NB, 256, 0, stream>>>(rowptr, partials, fill);
  scatter_kernel<<<(ET + 255) / 256, 256, 0, stream>>>(src, dst, fill, csr_src);
  repack_w<<<(3 * 16384 + 255) / 256, 256, 0, stream>>>(W[0], W[1], W[2], Wr);

  const int gemm_grid = (N_NODES + 63) / 64;
  const int agg_grid  = (N_NODES * 64 + 255) / 256;

  for (int L = 0; L < 3; ++L) {
    const float* fin = (L == 0) ? x : A;
    int doBN = (L > 0);
    const float* gg = doBN ? g[L - 1]  : (const float*)nullptr;
    const float* bb = doBN ? be[L - 1] : (const float*)nullptr;
    gemm_mfma<<<gemm_grid, 256, 0, stream>>>(fin, Wr + (size_t)L * 16384, bna, gg, bb,
                                             asrc[L], adst[L], Hbf, als, ald, doBN);
    fused_agg<<<agg_grid, 256, 0, stream>>>(rowptr, csr_src, (const unsigned*)Hbf,
                                            als, ald, A, (float*)d_out, b2,
                                            (L == 2) ? 2 : 0);
    if (L < 2) {
      hipMemsetAsync(bna, 0, 256 * sizeof(float), stream);
      bn_stats<<<1024, 256, 0, stream>>>(A, bna);
    }
  }
}